// Round 1
// baseline (37066.180 us; speedup 1.0000x reference)
//
#include <hip/hip_runtime.h>

constexpr int NN = 500000;
constexpr int NE = 16000000;

// ---------------- layer-1 pre-transform: t = x @ Wl1.T (10 -> 5) ----------------
__global__ void __launch_bounds__(256) transform0(const float* __restrict__ x,
                                                  const float* __restrict__ Wl1,
                                                  float* __restrict__ t) {
    int i = blockIdx.x * 256 + threadIdx.x;
    if (i >= NN) return;
    float xi[10];
#pragma unroll
    for (int k = 0; k < 10; ++k) xi[k] = x[i * 10 + k];
#pragma unroll
    for (int j = 0; j < 5; ++j) {
        float v = 0.f;
#pragma unroll
        for (int k = 0; k < 10; ++k) v += xi[k] * Wl1[j * 10 + k];
        t[i * 5 + j] = v;
    }
}

// ---------------- edge scatter-add of pre-transformed features ----------------
template <int F, bool COUNT>
__global__ void __launch_bounds__(256) edge_agg(const int* __restrict__ src,
                                                const int* __restrict__ dst,
                                                const float* __restrict__ t,
                                                float* __restrict__ agg,
                                                float* __restrict__ cnt) {
    int e = blockIdx.x * 256 + threadIdx.x;
    if (e >= NE) return;
    int s = src[e];
    int d = dst[e];
    if (COUNT) atomicAdd(&cnt[d], 1.0f);
#pragma unroll
    for (int f = 0; f < F; ++f) atomicAdd(&agg[d * F + f], t[s * F + f]);
}

// ---------------- inv = 1 / max(cnt, 1) ----------------
__global__ void __launch_bounds__(256) inv_kernel(const float* __restrict__ cnt,
                                                  float* __restrict__ inv) {
    int i = blockIdx.x * 256 + threadIdx.x;
    if (i >= NN) return;
    inv[i] = 1.0f / fmaxf(cnt[i], 1.0f);
}

// ---------------- fused node update ----------------
// hout = act(agg*inv + hin @ Wr.T + b); tnext = hout @ Wln.T; agg re-zeroed.
template <int FIN, int FOUT, int FNEXT, bool RELU>
__global__ void __launch_bounds__(256) node_update(const float* __restrict__ hin,
                                                   float* __restrict__ agg,
                                                   const float* __restrict__ inv,
                                                   const float* __restrict__ Wr,
                                                   const float* __restrict__ b,
                                                   const float* __restrict__ Wln,
                                                   float* __restrict__ hout,
                                                   float* __restrict__ tnext) {
    int i = blockIdx.x * 256 + threadIdx.x;
    if (i >= NN) return;
    float vin[FIN];
#pragma unroll
    for (int k = 0; k < FIN; ++k) vin[k] = hin[i * FIN + k];
    float iv = inv[i];
    float ho[FOUT];
#pragma unroll
    for (int j = 0; j < FOUT; ++j) {
        float v = agg[i * FOUT + j] * iv + b[j];
        agg[i * FOUT + j] = 0.f;  // pre-zero for the next layer's scatter
#pragma unroll
        for (int k = 0; k < FIN; ++k) v += vin[k] * Wr[j * FIN + k];
        if (RELU) v = fmaxf(v, 0.f);
        hout[i * FOUT + j] = v;
        ho[j] = v;
    }
    if constexpr (FNEXT > 0) {
#pragma unroll
        for (int j2 = 0; j2 < FNEXT; ++j2) {
            float v = 0.f;
#pragma unroll
            for (int j = 0; j < FOUT; ++j) v += ho[j] * Wln[j2 * FOUT + j];
            tnext[i * FNEXT + j2] = v;
        }
    }
}

extern "C" void kernel_launch(void* const* d_in, const int* in_sizes, int n_in,
                              void* d_out, int out_size, void* d_ws, size_t ws_size,
                              hipStream_t stream) {
    (void)in_sizes; (void)n_in; (void)out_size; (void)ws_size;
    const float* x    = (const float*)d_in[0];
    const int*   ei   = (const int*)d_in[1];
    const float* Wl1  = (const float*)d_in[2];
    const float* Wr1  = (const float*)d_in[3];
    const float* b1   = (const float*)d_in[4];
    const float* Wlm  = (const float*)d_in[5];
    const float* Wrm  = (const float*)d_in[6];
    const float* bm   = (const float*)d_in[7];
    const float* Wl10 = (const float*)d_in[8];
    const float* Wr10 = (const float*)d_in[9];
    const float* b10  = (const float*)d_in[10];
    float* out = (float*)d_out;

    float* ws  = (float*)d_ws;
    float* cnt = ws;            // N
    float* agg = ws + NN;       // 5N (cnt+agg adjacent -> one memset)
    float* inv = ws + 6 * NN;   // N
    float* t   = ws + 7 * NN;   // 5N
    float* hA  = ws + 12 * NN;  // 5N
    float* hB  = ws + 17 * NN;  // 5N   (total 22N floats = 44 MB)

    const int* src = ei;
    const int* dst = ei + NE;

    // zero cnt + agg
    hipMemsetAsync(ws, 0, (size_t)6 * NN * sizeof(float), stream);

    dim3 blk(256);
    dim3 nb((NN + 255) / 256);
    dim3 eb((NE + 255) / 256);

    // layer 1 (10 -> 5), count fused into first edge pass
    transform0<<<nb, blk, 0, stream>>>(x, Wl1, t);
    edge_agg<5, true><<<eb, blk, 0, stream>>>(src, dst, t, agg, cnt);
    inv_kernel<<<nb, blk, 0, stream>>>(cnt, inv);
    node_update<10, 5, 5, true><<<nb, blk, 0, stream>>>(x, agg, inv, Wr1, b1,
                                                        Wlm + 0, hA, t);
    const float* hcur = hA;
    float* hnext = hB;

    // 8 middle layers (5 -> 5)
    for (int l = 1; l <= 8; ++l) {
        edge_agg<5, false><<<eb, blk, 0, stream>>>(src, dst, t, agg, nullptr);
        const float* Wr = Wrm + (l - 1) * 25;
        const float* bb = bm + (l - 1) * 5;
        if (l < 8) {
            node_update<5, 5, 5, true><<<nb, blk, 0, stream>>>(
                hcur, agg, inv, Wr, bb, Wlm + l * 25, hnext, t);
        } else {
            // last mid layer: pre-transform for the final (5 -> 1) layer
            node_update<5, 5, 1, true><<<nb, blk, 0, stream>>>(
                hcur, agg, inv, Wr, bb, Wl10, hnext, t);
        }
        const float* tmp = hcur; hcur = hnext; hnext = (float*)tmp;
    }

    // layer 10 (5 -> 1), aggregate a single float per edge, no relu
    edge_agg<1, false><<<eb, blk, 0, stream>>>(src, dst, t, agg, nullptr);
    node_update<5, 1, 0, false><<<nb, blk, 0, stream>>>(hcur, agg, inv, Wr10, b10,
                                                        nullptr, out, nullptr);
}

// Round 2
// 5438.968 us; speedup vs baseline: 6.8149x; 6.8149x over previous
//
#include <hip/hip_runtime.h>

constexpr int NN = 500000;
constexpr int NE = 16000000;
constexpr int NB_NODE = (NN + 255) / 256;   // 1954

// ---------------- layer-1 pre-transform: t = x @ Wl1.T (10 -> 5), stride 8 ----------------
__global__ void __launch_bounds__(256) transform0(const float* __restrict__ x,
                                                  const float* __restrict__ Wl1,
                                                  float* __restrict__ t) {
    int i = blockIdx.x * 256 + threadIdx.x;
    if (i >= NN) return;
    float xi[10];
#pragma unroll
    for (int k = 0; k < 10; ++k) xi[k] = x[i * 10 + k];
#pragma unroll
    for (int j = 0; j < 5; ++j) {
        float v = 0.f;
#pragma unroll
        for (int k = 0; k < 10; ++k) v += xi[k] * Wl1[j * 10 + k];
        t[i * 8 + j] = v;
    }
}

// ---------------- degree histogram ----------------
__global__ void __launch_bounds__(256) histogram(const int* __restrict__ dst,
                                                 int* __restrict__ cnt) {
    int e = blockIdx.x * 256 + threadIdx.x;
    if (e >= NE) return;
    atomicAdd(&cnt[dst[e]], 1);
}

// ---------------- scan stage A: per-block exclusive scan ----------------
__global__ void __launch_bounds__(256) scanA(const int* __restrict__ cnt,
                                             int* __restrict__ bscan,
                                             int* __restrict__ bsums) {
    __shared__ int sh[256];
    int tid = threadIdx.x;
    int i = blockIdx.x * 256 + tid;
    int v = (i < NN) ? cnt[i] : 0;
    sh[tid] = v;
    __syncthreads();
    for (int off = 1; off < 256; off <<= 1) {
        int add = (tid >= off) ? sh[tid - off] : 0;
        __syncthreads();
        sh[tid] += add;
        __syncthreads();
    }
    if (i < NN) bscan[i] = sh[tid] - v;   // exclusive
    if (tid == 255) bsums[blockIdx.x] = sh[255];
}

// ---------------- scan stage B: exclusive scan of block sums (single block) ----------------
__global__ void __launch_bounds__(256) scanB(int* __restrict__ bs, int n) {
    __shared__ int tot[256];
    int tid = threadIdx.x;
    int base = tid * 8;
    int v[8];
    int sum = 0;
#pragma unroll
    for (int k = 0; k < 8; ++k) {
        int idx = base + k;
        v[k] = (idx < n) ? bs[idx] : 0;
        sum += v[k];
    }
    tot[tid] = sum;
    __syncthreads();
    for (int off = 1; off < 256; off <<= 1) {
        int add = (tid >= off) ? tot[tid - off] : 0;
        __syncthreads();
        tot[tid] += add;
        __syncthreads();
    }
    int run = tot[tid] - sum;   // exclusive prefix for this chunk
#pragma unroll
    for (int k = 0; k < 8; ++k) {
        int idx = base + k;
        if (idx < n) { bs[idx] = run; run += v[k]; }
    }
}

// ---------------- scan stage C: combine -> row_ptr + cursor ----------------
__global__ void __launch_bounds__(256) scanC(const int* __restrict__ bscan,
                                             const int* __restrict__ bsums,
                                             int* __restrict__ row_ptr,
                                             int* __restrict__ cursor) {
    int i = blockIdx.x * 256 + threadIdx.x;
    if (i >= NN) return;
    int r = bscan[i] + bsums[i >> 8];
    row_ptr[i] = r;
    cursor[i] = r;
    if (i == 0) row_ptr[NN] = NE;
}

// ---------------- CSR fill ----------------
__global__ void __launch_bounds__(256) fill_csr(const int* __restrict__ src,
                                                const int* __restrict__ dst,
                                                int* __restrict__ cursor,
                                                int* __restrict__ csr_src) {
    int e = blockIdx.x * 256 + threadIdx.x;
    if (e >= NE) return;
    int d = dst[e];
    int pos = atomicAdd(&cursor[d], 1);
    csr_src[pos] = src[e];
}

// ---------------- fused gather + node update ----------------
// acc = sum_{s in N(i)} t[s]; hout = act(acc/deg + hin@Wr.T + b); tnext = hout@Wln.T
template <int FIN, int FOUT, int FNEXT, bool RELU, int TSIN, int TSOUT>
__global__ void __launch_bounds__(256) gather_update(const int* __restrict__ row_ptr,
                                                     const int* __restrict__ csr_src,
                                                     const float* __restrict__ t,
                                                     const float* __restrict__ hin,
                                                     const float* __restrict__ Wr,
                                                     const float* __restrict__ b,
                                                     const float* __restrict__ Wln,
                                                     float* __restrict__ hout,
                                                     float* __restrict__ tnext) {
    int i = blockIdx.x * 256 + threadIdx.x;
    if (i >= NN) return;
    int beg = row_ptr[i];
    int end = row_ptr[i + 1];
    float acc[FOUT];
#pragma unroll
    for (int f = 0; f < FOUT; ++f) acc[f] = 0.f;

    int j = beg;
    for (; j + 1 < end; j += 2) {   // 2 independent gather chains in flight
        int s0 = csr_src[j];
        int s1 = csr_src[j + 1];
        if constexpr (FOUT == 5 && TSIN == 8) {
            float4 p0 = *(const float4*)(t + (size_t)s0 * 8);
            float4 p1 = *(const float4*)(t + (size_t)s1 * 8);
            float q0 = t[(size_t)s0 * 8 + 4];
            float q1 = t[(size_t)s1 * 8 + 4];
            acc[0] += p0.x + p1.x; acc[1] += p0.y + p1.y;
            acc[2] += p0.z + p1.z; acc[3] += p0.w + p1.w;
            acc[4] += q0 + q1;
        } else {
#pragma unroll
            for (int f = 0; f < FOUT; ++f)
                acc[f] += t[(size_t)s0 * TSIN + f] + t[(size_t)s1 * TSIN + f];
        }
    }
    if (j < end) {
        int s0 = csr_src[j];
        if constexpr (FOUT == 5 && TSIN == 8) {
            float4 p0 = *(const float4*)(t + (size_t)s0 * 8);
            acc[0] += p0.x; acc[1] += p0.y; acc[2] += p0.z; acc[3] += p0.w;
            acc[4] += t[(size_t)s0 * 8 + 4];
        } else {
#pragma unroll
            for (int f = 0; f < FOUT; ++f) acc[f] += t[(size_t)s0 * TSIN + f];
        }
    }

    float iv = 1.0f / (float)max(end - beg, 1);
    float vin[FIN];
#pragma unroll
    for (int k = 0; k < FIN; ++k) vin[k] = hin[(size_t)i * FIN + k];
    float ho[FOUT];
#pragma unroll
    for (int jo = 0; jo < FOUT; ++jo) {
        float v = acc[jo] * iv + b[jo];
#pragma unroll
        for (int k = 0; k < FIN; ++k) v += vin[k] * Wr[jo * FIN + k];
        if (RELU) v = fmaxf(v, 0.f);
        hout[(size_t)i * FOUT + jo] = v;
        ho[jo] = v;
    }
    if constexpr (FNEXT > 0) {
#pragma unroll
        for (int j2 = 0; j2 < FNEXT; ++j2) {
            float v = 0.f;
#pragma unroll
            for (int jo = 0; jo < FOUT; ++jo) v += ho[jo] * Wln[j2 * FOUT + jo];
            tnext[(size_t)i * TSOUT + j2] = v;
        }
    }
}

extern "C" void kernel_launch(void* const* d_in, const int* in_sizes, int n_in,
                              void* d_out, int out_size, void* d_ws, size_t ws_size,
                              hipStream_t stream) {
    (void)in_sizes; (void)n_in; (void)out_size; (void)ws_size;
    const float* x    = (const float*)d_in[0];
    const int*   ei   = (const int*)d_in[1];
    const float* Wl1  = (const float*)d_in[2];
    const float* Wr1  = (const float*)d_in[3];
    const float* b1   = (const float*)d_in[4];
    const float* Wlm  = (const float*)d_in[5];
    const float* Wrm  = (const float*)d_in[6];
    const float* bm   = (const float*)d_in[7];
    const float* Wl10 = (const float*)d_in[8];
    const float* Wr10 = (const float*)d_in[9];
    const float* b10  = (const float*)d_in[10];
    float* out = (float*)d_out;

    const int* src = ei;
    const int* dst = ei + NE;

    // workspace layout (units of 4 bytes)
    int* wsI = (int*)d_ws;
    int* row_ptr = wsI;                         // NN+1  (pad to 500224)
    int* cursor  = wsI + 500224;                // NN
    int* cnt     = wsI + 1000448;               // NN
    int* bscan   = wsI + 1500672;               // NN
    int* bsums   = wsI + 2000896;               // 1954 (pad to 2048)
    int* csr_src = wsI + 2002944;               // NE
    float* tA    = (float*)(wsI + 18002944);    // 8*NN  (32B-aligned rows)
    float* tB    = tA + 8 * NN;                 // 8*NN
    float* hA    = tB + 8 * NN;                 // 5*NN
    float* hB    = hA + 5 * NN;                 // 5*NN   total ~126 MB

    dim3 blk(256);
    dim3 nb(NB_NODE);
    dim3 eb((NE + 255) / 256);

    // ---- CSR build ----
    hipMemsetAsync(cnt, 0, (size_t)NN * sizeof(int), stream);
    histogram<<<eb, blk, 0, stream>>>(dst, cnt);
    scanA<<<nb, blk, 0, stream>>>(cnt, bscan, bsums);
    scanB<<<dim3(1), blk, 0, stream>>>(bsums, NB_NODE);
    scanC<<<nb, blk, 0, stream>>>(bscan, bsums, row_ptr, cursor);
    fill_csr<<<eb, blk, 0, stream>>>(src, dst, cursor, csr_src);

    // ---- layer 1 (10 -> 5) ----
    transform0<<<nb, blk, 0, stream>>>(x, Wl1, tA);
    gather_update<10, 5, 5, true, 8, 8><<<nb, blk, 0, stream>>>(
        row_ptr, csr_src, tA, x, Wr1, b1, Wlm, hA, tB);

    // ---- middle layers 0..6 (5 -> 5, next pre-transform 5) ----
    const float* tcur = tB; float* tnxt = tA;
    const float* hcur = hA; float* hnext = hB;
    for (int mi = 0; mi < 7; ++mi) {
        gather_update<5, 5, 5, true, 8, 8><<<nb, blk, 0, stream>>>(
            row_ptr, csr_src, tcur, hcur, Wrm + mi * 25, bm + mi * 5,
            Wlm + (mi + 1) * 25, hnext, tnxt);
        const float* tt = tcur; tcur = tnxt; tnxt = (float*)tt;
        const float* th = hcur; hcur = hnext; hnext = (float*)th;
    }
    // ---- middle layer 7: next pre-transform is final (5 -> 1), stride-1 t ----
    gather_update<5, 5, 1, true, 8, 1><<<nb, blk, 0, stream>>>(
        row_ptr, csr_src, tcur, hcur, Wrm + 7 * 25, bm + 7 * 5,
        Wl10, hnext, tnxt);   // tnxt used as stride-1 [NN] array
    // ---- final layer (5 -> 1), no relu ----
    gather_update<5, 1, 0, false, 1, 1><<<nb, blk, 0, stream>>>(
        row_ptr, csr_src, tnxt, hnext, Wr10, b10, nullptr, out, nullptr);
}

// Round 3
// 5046.888 us; speedup vs baseline: 7.3444x; 1.0777x over previous
//
#include <hip/hip_runtime.h>

constexpr int NN = 500000;
constexpr int NE = 16000000;
constexpr int NBUCK = (NN + 255) / 256;   // 1954 buckets of 256 dst nodes
constexpr int CAP = 9216;                 // mean 8188, sd ~90 -> z=11.4, safe
constexpr int NB_NODE = (NN + 255) / 256;

// ---------------- pass 1: bucket edges by dst>>8, pack (src<<8)|(dst&255) ----------------
__global__ void __launch_bounds__(256) bucket_pass(const int* __restrict__ src,
                                                   const int* __restrict__ dst,
                                                   int* __restrict__ bcnt,
                                                   int* __restrict__ bstore) {
    int e0 = (blockIdx.x * 256 + threadIdx.x) * 4;
    if (e0 >= NE) return;
    int4 s = *(const int4*)(src + e0);
    int4 d = *(const int4*)(dst + e0);
    int sv[4] = {s.x, s.y, s.z, s.w};
    int dv[4] = {d.x, d.y, d.z, d.w};
#pragma unroll
    for (int k = 0; k < 4; ++k) {
        int b = dv[k] >> 8;
        int pos = atomicAdd(&bcnt[b], 1);
        if (pos < CAP) bstore[(size_t)b * CAP + pos] = (sv[k] << 8) | (dv[k] & 255);
    }
}

// ---------------- bucket base: exclusive scan of 1954 counts (single block) ----------------
__global__ void __launch_bounds__(256) bucket_scan(const int* __restrict__ bcnt,
                                                   int* __restrict__ bbase, int n) {
    __shared__ int tot[256];
    int tid = threadIdx.x;
    int v[8];
    int sum = 0;
#pragma unroll
    for (int k = 0; k < 8; ++k) {
        int idx = tid * 8 + k;
        v[k] = (idx < n) ? bcnt[idx] : 0;
        sum += v[k];
    }
    tot[tid] = sum;
    __syncthreads();
    for (int off = 1; off < 256; off <<= 1) {
        int add = (tid >= off) ? tot[tid - off] : 0;
        __syncthreads();
        tot[tid] += add;
        __syncthreads();
    }
    int run = tot[tid] - sum;
#pragma unroll
    for (int k = 0; k < 8; ++k) {
        int idx = tid * 8 + k;
        if (idx < n) { bbase[idx] = run; run += v[k]; }
    }
}

// ---------------- pass 2: per-bucket LDS sort -> row_ptr + csr_src ----------------
__global__ void __launch_bounds__(256) csr_place(const int* __restrict__ bcnt,
                                                 const int* __restrict__ bbase,
                                                 const int* __restrict__ bstore,
                                                 int* __restrict__ row_ptr,
                                                 int* __restrict__ csr_src) {
    __shared__ int ent[CAP];
    __shared__ int hist[256];
    __shared__ int cur[256];
    int b = blockIdx.x;
    int tid = threadIdx.x;
    int n = bcnt[b];
    if (n > CAP) n = CAP;
    int base = bbase[b];
    hist[tid] = 0;
    const int* bs = bstore + (size_t)b * CAP;
    for (int k = tid; k < n; k += 256) ent[k] = bs[k];
    __syncthreads();
    for (int k = tid; k < n; k += 256) atomicAdd(&hist[ent[k] & 255], 1);
    __syncthreads();
    // exclusive block scan of hist
    int v = hist[tid];
    int run = v;
    __shared__ int sc[256];
    sc[tid] = run;
    __syncthreads();
    for (int off = 1; off < 256; off <<= 1) {
        int add = (tid >= off) ? sc[tid - off] : 0;
        __syncthreads();
        sc[tid] += add;
        __syncthreads();
    }
    int excl = sc[tid] - v;
    int node = b * 256 + tid;
    if (node < NN) row_ptr[node] = base + excl;
    if (b == 0 && tid == 0) row_ptr[NN] = NE;
    cur[tid] = excl;
    __syncthreads();
    for (int k = tid; k < n; k += 256) {
        int e = ent[k];
        int p = atomicAdd(&cur[e & 255], 1);
        csr_src[base + p] = e >> 8;   // e < 2^27, sign-safe
    }
}

// ---------------- layer-1 pre-transform: t = x @ Wl1.T (10 -> 5), stride 8 ----------------
__global__ void __launch_bounds__(256) transform0(const float* __restrict__ x,
                                                  const float* __restrict__ Wl1,
                                                  float* __restrict__ t) {
    int i = blockIdx.x * 256 + threadIdx.x;
    if (i >= NN) return;
    float xi[10];
#pragma unroll
    for (int k = 0; k < 10; ++k) xi[k] = x[i * 10 + k];
#pragma unroll
    for (int j = 0; j < 5; ++j) {
        float v = 0.f;
#pragma unroll
        for (int k = 0; k < 10; ++k) v += xi[k] * Wl1[j * 10 + k];
        t[i * 8 + j] = v;
    }
}

// ---------------- fused gather + node update ----------------
template <int FIN, int FOUT, int FNEXT, bool RELU, int TSIN, int TSOUT>
__global__ void __launch_bounds__(256) gather_update(const int* __restrict__ row_ptr,
                                                     const int* __restrict__ csr_src,
                                                     const float* __restrict__ t,
                                                     const float* __restrict__ hin,
                                                     const float* __restrict__ Wr,
                                                     const float* __restrict__ b,
                                                     const float* __restrict__ Wln,
                                                     float* __restrict__ hout,
                                                     float* __restrict__ tnext) {
    int i = blockIdx.x * 256 + threadIdx.x;
    if (i >= NN) return;
    int beg = row_ptr[i];
    int end = row_ptr[i + 1];
    float acc[FOUT];
#pragma unroll
    for (int f = 0; f < FOUT; ++f) acc[f] = 0.f;

    int j = beg;
    if constexpr (FOUT == 5 && TSIN == 8) {
        for (; j + 3 < end; j += 4) {   // 4 independent gather chains
            int s0 = csr_src[j], s1 = csr_src[j + 1];
            int s2 = csr_src[j + 2], s3 = csr_src[j + 3];
            float4 p0 = *(const float4*)(t + (size_t)s0 * 8);
            float4 p1 = *(const float4*)(t + (size_t)s1 * 8);
            float4 p2 = *(const float4*)(t + (size_t)s2 * 8);
            float4 p3 = *(const float4*)(t + (size_t)s3 * 8);
            float q0 = t[(size_t)s0 * 8 + 4], q1 = t[(size_t)s1 * 8 + 4];
            float q2 = t[(size_t)s2 * 8 + 4], q3 = t[(size_t)s3 * 8 + 4];
            acc[0] += (p0.x + p1.x) + (p2.x + p3.x);
            acc[1] += (p0.y + p1.y) + (p2.y + p3.y);
            acc[2] += (p0.z + p1.z) + (p2.z + p3.z);
            acc[3] += (p0.w + p1.w) + (p2.w + p3.w);
            acc[4] += (q0 + q1) + (q2 + q3);
        }
        for (; j < end; ++j) {
            int s0 = csr_src[j];
            float4 p0 = *(const float4*)(t + (size_t)s0 * 8);
            acc[0] += p0.x; acc[1] += p0.y; acc[2] += p0.z; acc[3] += p0.w;
            acc[4] += t[(size_t)s0 * 8 + 4];
        }
    } else {
        for (; j + 3 < end; j += 4) {
            int s0 = csr_src[j], s1 = csr_src[j + 1];
            int s2 = csr_src[j + 2], s3 = csr_src[j + 3];
#pragma unroll
            for (int f = 0; f < FOUT; ++f)
                acc[f] += (t[(size_t)s0 * TSIN + f] + t[(size_t)s1 * TSIN + f]) +
                          (t[(size_t)s2 * TSIN + f] + t[(size_t)s3 * TSIN + f]);
        }
        for (; j < end; ++j) {
            int s0 = csr_src[j];
#pragma unroll
            for (int f = 0; f < FOUT; ++f) acc[f] += t[(size_t)s0 * TSIN + f];
        }
    }

    float iv = 1.0f / (float)max(end - beg, 1);
    float vin[FIN];
#pragma unroll
    for (int k = 0; k < FIN; ++k) vin[k] = hin[(size_t)i * FIN + k];
    float ho[FOUT];
#pragma unroll
    for (int jo = 0; jo < FOUT; ++jo) {
        float v = acc[jo] * iv + b[jo];
#pragma unroll
        for (int k = 0; k < FIN; ++k) v += vin[k] * Wr[jo * FIN + k];
        if (RELU) v = fmaxf(v, 0.f);
        hout[(size_t)i * FOUT + jo] = v;
        ho[jo] = v;
    }
    if constexpr (FNEXT > 0) {
#pragma unroll
        for (int j2 = 0; j2 < FNEXT; ++j2) {
            float v = 0.f;
#pragma unroll
            for (int jo = 0; jo < FOUT; ++jo) v += ho[jo] * Wln[j2 * FOUT + jo];
            tnext[(size_t)i * TSOUT + j2] = v;
        }
    }
}

extern "C" void kernel_launch(void* const* d_in, const int* in_sizes, int n_in,
                              void* d_out, int out_size, void* d_ws, size_t ws_size,
                              hipStream_t stream) {
    (void)in_sizes; (void)n_in; (void)out_size; (void)ws_size;
    const float* x    = (const float*)d_in[0];
    const int*   ei   = (const int*)d_in[1];
    const float* Wl1  = (const float*)d_in[2];
    const float* Wr1  = (const float*)d_in[3];
    const float* b1   = (const float*)d_in[4];
    const float* Wlm  = (const float*)d_in[5];
    const float* Wrm  = (const float*)d_in[6];
    const float* bm   = (const float*)d_in[7];
    const float* Wl10 = (const float*)d_in[8];
    const float* Wr10 = (const float*)d_in[9];
    const float* b10  = (const float*)d_in[10];
    float* out = (float*)d_out;

    const int* src = ei;
    const int* dst = ei + NE;

    // workspace layout (4-byte units)
    int* wsI = (int*)d_ws;
    int* csr_src = wsI;                         // 16,000,000
    int* row_ptr = wsI + 16000000;              // NN+1 -> pad 500224
    int* bcnt    = wsI + 16500224;              // 1954 -> pad 2048
    int* bbase   = wsI + 16502272;              // 1954 -> pad 2048
    int* bstore  = wsI + 16504320;              // NBUCK*CAP = 18,008,064
    // bstore is dead after csr_place -> alias feature tables onto it
    float* tA = (float*)(wsI + 16504320);       // 8*NN = 4,000,000
    float* tB = tA + 8 * NN;                    // 8*NN
    float* hA = tB + 8 * NN;                    // 5*NN
    float* hB = hA + 5 * NN;                    // 5*NN (26M floats total < bstore's 18M? no:)
    // NOTE: alias region needs 26M ints but bstore is 18M -> extend past bstore.
    // total ws usage = 16504320 + max(18008064, 26000000) = 42,504,320 ints ~= 170 MB

    dim3 blk(256);
    dim3 nb(NB_NODE);

    // ---- CSR build (bucketed) ----
    hipMemsetAsync(bcnt, 0, 2048 * sizeof(int), stream);
    bucket_pass<<<dim3(NE / 1024), blk, 0, stream>>>(src, dst, bcnt, bstore);
    bucket_scan<<<dim3(1), blk, 0, stream>>>(bcnt, bbase, NBUCK);
    csr_place<<<dim3(NBUCK), blk, 0, stream>>>(bcnt, bbase, bstore, row_ptr, csr_src);

    // ---- layer 1 (10 -> 5) ----
    transform0<<<nb, blk, 0, stream>>>(x, Wl1, tA);
    gather_update<10, 5, 5, true, 8, 8><<<nb, blk, 0, stream>>>(
        row_ptr, csr_src, tA, x, Wr1, b1, Wlm, hA, tB);

    // ---- middle layers 0..6 (5 -> 5) ----
    const float* tcur = tB; float* tnxt = tA;
    const float* hcur = hA; float* hnext = hB;
    for (int mi = 0; mi < 7; ++mi) {
        gather_update<5, 5, 5, true, 8, 8><<<nb, blk, 0, stream>>>(
            row_ptr, csr_src, tcur, hcur, Wrm + mi * 25, bm + mi * 5,
            Wlm + (mi + 1) * 25, hnext, tnxt);
        const float* tt = tcur; tcur = tnxt; tnxt = (float*)tt;
        const float* th = hcur; hcur = hnext; hnext = (float*)th;
    }
    // ---- middle layer 7: next pre-transform is final (5 -> 1), stride-1 ----
    gather_update<5, 5, 1, true, 8, 1><<<nb, blk, 0, stream>>>(
        row_ptr, csr_src, tcur, hcur, Wrm + 7 * 25, bm + 7 * 5,
        Wl10, hnext, tnxt);
    // ---- final layer (5 -> 1), no relu ----
    gather_update<5, 1, 0, false, 1, 1><<<nb, blk, 0, stream>>>(
        row_ptr, csr_src, tnxt, hnext, Wr10, b10, nullptr, out, nullptr);
}

// Round 4
// 4764.702 us; speedup vs baseline: 7.7793x; 1.0592x over previous
//
#include <hip/hip_runtime.h>

constexpr int NN = 500000;
constexpr int NE = 16000000;
constexpr int BN = 512;                    // dst nodes per bucket
constexpr int NBUCK = (NN + BN - 1) / BN;  // 977
constexpr int NSUB = 8;                    // per-XCD sub-buffers
constexpr int CAPS = 2560;                 // per-sub cap: mean 2047, sd ~45 -> 11 sigma
constexpr int NB_NODE = (NN + 255) / 256;

// ---------------- bucket edges by dst>>9 into per-(bucket, blockIdx%8) sub-buffers ----------------
__global__ void __launch_bounds__(256) bucket_pass(const int* __restrict__ src,
                                                   const int* __restrict__ dst,
                                                   int* __restrict__ bcnt,
                                                   int* __restrict__ bstore) {
    int e0 = (blockIdx.x * 256 + threadIdx.x) * 4;   // NE % 1024 == 0, no tail
    int sub = blockIdx.x & (NSUB - 1);               // likely-XCD id (locality heuristic only)
    int4 s = *(const int4*)(src + e0);
    int4 d = *(const int4*)(dst + e0);
    int sv[4] = {s.x, s.y, s.z, s.w};
    int dv[4] = {d.x, d.y, d.z, d.w};
#pragma unroll
    for (int k = 0; k < 4; ++k) {
        int idx = (dv[k] >> 9) * NSUB + sub;
        int pos = atomicAdd(&bcnt[idx], 1);
        if (pos < CAPS)
            bstore[(size_t)idx * CAPS + pos] = (sv[k] << 9) | (dv[k] & (BN - 1));
    }
}

// ---------------- layer-1 pre-transform: t = x @ Wl1.T (10 -> 5), stride 8 ----------------
__global__ void __launch_bounds__(256) transform0(const float* __restrict__ x,
                                                  const float* __restrict__ Wl1,
                                                  float* __restrict__ t) {
    int i = blockIdx.x * 256 + threadIdx.x;
    if (i >= NN) return;
    float xi[10];
#pragma unroll
    for (int k = 0; k < 10; ++k) xi[k] = x[i * 10 + k];
#pragma unroll
    for (int j = 0; j < 5; ++j) {
        float v = 0.f;
#pragma unroll
        for (int k = 0; k < 10; ++k) v += xi[k] * Wl1[j * 10 + k];
        t[i * 8 + j] = v;
    }
}

// ---------------- fused edge-parallel gather (LDS accumulate) + node update ----------------
// block = one bucket of 512 dst nodes. acc in LDS; edges streamed coalesced.
template <int FIN, int FOUT, int FNEXT, bool RELU, bool FIRST, int TSIN, int TSOUT>
__global__ void __launch_bounds__(256) bucket_gather(const int* __restrict__ bcnt,
                                                     const int* __restrict__ bstore,
                                                     const float* __restrict__ t,
                                                     const float* __restrict__ hin,
                                                     const float* __restrict__ Wr,
                                                     const float* __restrict__ b,
                                                     const float* __restrict__ Wln,
                                                     float* __restrict__ inv,
                                                     float* __restrict__ hout,
                                                     float* __restrict__ tnext) {
    __shared__ float acc[BN * FOUT];
    __shared__ float scnt[FIRST ? BN : 1];
    const int bkt = blockIdx.x;
    const int tid = threadIdx.x;
    for (int k = tid; k < BN * FOUT; k += 256) acc[k] = 0.f;
    if (FIRST) {
        scnt[tid] = 0.f;
        scnt[tid + 256] = 0.f;
    }
    __syncthreads();

    auto process = [&](int e) {
        int s = e >> 9;
        int d = e & (BN - 1);
        if constexpr (TSIN == 8 && FOUT == 5) {
            float4 p = *(const float4*)(t + (size_t)s * 8);
            float q = t[(size_t)s * 8 + 4];
            atomicAdd(&acc[d * 5 + 0], p.x);
            atomicAdd(&acc[d * 5 + 1], p.y);
            atomicAdd(&acc[d * 5 + 2], p.z);
            atomicAdd(&acc[d * 5 + 3], p.w);
            atomicAdd(&acc[d * 5 + 4], q);
        } else {
#pragma unroll
            for (int f = 0; f < FOUT; ++f)
                atomicAdd(&acc[d * FOUT + f], t[(size_t)s * TSIN + f]);
        }
        if (FIRST) atomicAdd(&scnt[d], 1.f);
    };

#pragma unroll 1
    for (int sub = 0; sub < NSUB; ++sub) {
        int idx = bkt * NSUB + sub;
        int n = bcnt[idx];
        if (n > CAPS) n = CAPS;
        const int* bs = bstore + (size_t)idx * CAPS;
        int k = tid;
        for (; k + 256 < n; k += 512) {   // 2 edges in flight per thread
            int e0 = bs[k];
            int e1 = bs[k + 256];
            process(e0);
            process(e1);
        }
        if (k < n) process(bs[k]);
    }
    __syncthreads();

    // ---- node update: 2 nodes per thread ----
#pragma unroll
    for (int r = 0; r < 2; ++r) {
        int local = tid + r * 256;
        int node = bkt * BN + local;
        if (node >= NN) continue;
        float iv;
        if (FIRST) {
            iv = 1.0f / fmaxf(scnt[local], 1.0f);
            inv[node] = iv;
        } else {
            iv = inv[node];
        }
        float vin[FIN];
#pragma unroll
        for (int k = 0; k < FIN; ++k) vin[k] = hin[(size_t)node * FIN + k];
        float ho[FOUT];
#pragma unroll
        for (int jo = 0; jo < FOUT; ++jo) {
            float v = acc[local * FOUT + jo] * iv + b[jo];
#pragma unroll
            for (int k = 0; k < FIN; ++k) v += vin[k] * Wr[jo * FIN + k];
            if (RELU) v = fmaxf(v, 0.f);
            hout[(size_t)node * FOUT + jo] = v;
            ho[jo] = v;
        }
        if constexpr (FNEXT > 0) {
#pragma unroll
            for (int j2 = 0; j2 < FNEXT; ++j2) {
                float v = 0.f;
#pragma unroll
                for (int jo = 0; jo < FOUT; ++jo) v += ho[jo] * Wln[j2 * FOUT + jo];
                tnext[(size_t)node * TSOUT + j2] = v;
            }
        }
    }
}

extern "C" void kernel_launch(void* const* d_in, const int* in_sizes, int n_in,
                              void* d_out, int out_size, void* d_ws, size_t ws_size,
                              hipStream_t stream) {
    (void)in_sizes; (void)n_in; (void)out_size; (void)ws_size;
    const float* x    = (const float*)d_in[0];
    const int*   ei   = (const int*)d_in[1];
    const float* Wl1  = (const float*)d_in[2];
    const float* Wr1  = (const float*)d_in[3];
    const float* b1   = (const float*)d_in[4];
    const float* Wlm  = (const float*)d_in[5];
    const float* Wrm  = (const float*)d_in[6];
    const float* bm   = (const float*)d_in[7];
    const float* Wl10 = (const float*)d_in[8];
    const float* Wr10 = (const float*)d_in[9];
    const float* b10  = (const float*)d_in[10];
    float* out = (float*)d_out;

    const int* src = ei;
    const int* dst = ei + NE;

    // workspace layout (4-byte units); total ~134 MB
    int* wsI = (int*)d_ws;
    int*   bcnt   = wsI;                       // 7816 -> pad 8192
    int*   bstore = wsI + 8192;                // NBUCK*NSUB*CAPS = 20,008,960
    float* inv    = (float*)(wsI + 20017152);  // NN -> pad 500224
    float* tA     = (float*)(wsI + 20517376);  // 8*NN (16B-aligned rows)
    float* tB     = tA + 8 * NN;               // 8*NN
    float* hA     = tB + 8 * NN;               // 5*NN
    float* hB     = hA + 5 * NN;               // 5*NN

    dim3 blk(256);
    dim3 nb(NB_NODE);
    dim3 gb(NBUCK);

    // ---- bucket build (replaces histogram/scan/fill CSR) ----
    hipMemsetAsync(bcnt, 0, 8192 * sizeof(int), stream);
    bucket_pass<<<dim3(NE / 1024), blk, 0, stream>>>(src, dst, bcnt, bstore);

    // ---- layer 1 (10 -> 5); counts degree, writes inv ----
    transform0<<<nb, blk, 0, stream>>>(x, Wl1, tA);
    bucket_gather<10, 5, 5, true, true, 8, 8><<<gb, blk, 0, stream>>>(
        bcnt, bstore, tA, x, Wr1, b1, Wlm, inv, hA, tB);

    // ---- middle layers 0..6 (5 -> 5) ----
    const float* tcur = tB; float* tnxt = tA;
    const float* hcur = hA; float* hnext = hB;
    for (int mi = 0; mi < 7; ++mi) {
        bucket_gather<5, 5, 5, true, false, 8, 8><<<gb, blk, 0, stream>>>(
            bcnt, bstore, tcur, hcur, Wrm + mi * 25, bm + mi * 5,
            Wlm + (mi + 1) * 25, inv, hnext, tnxt);
        const float* tt = tcur; tcur = tnxt; tnxt = (float*)tt;
        const float* th = hcur; hcur = hnext; hnext = (float*)th;
    }
    // ---- middle layer 7: next pre-transform is final (5 -> 1), stride-1 t ----
    bucket_gather<5, 5, 1, true, false, 8, 1><<<gb, blk, 0, stream>>>(
        bcnt, bstore, tcur, hcur, Wrm + 7 * 25, bm + 7 * 5,
        Wl10, inv, hnext, tnxt);
    // ---- final layer (5 -> 1), no relu; t-table is 2 MB -> L2-resident ----
    bucket_gather<5, 1, 0, false, false, 1, 1><<<gb, blk, 0, stream>>>(
        bcnt, bstore, tnxt, hnext, Wr10, b10, nullptr, inv, out, nullptr);
}